// Round 2
// baseline (1457.932 us; speedup 1.0000x reference)
//
#include <hip/hip_runtime.h>
#include <hip/hip_bf16.h>

#define NRN   4096
#define HISTD 64
#define MIDD  128
#define BATCHD 1024
#define SW1   66   // LDS row stride (bf16 elems) for w1T [mid][k]: 66 -> conflict-free transpose

typedef __attribute__((ext_vector_type(8))) short bf16x8_t;
typedef __attribute__((ext_vector_type(4))) float f32x4_t;

__device__ __forceinline__ unsigned short bf16_rne(float f) {
    unsigned u = __float_as_uint(f);
    u += 0x7FFFu + ((u >> 16) & 1u);
    return (unsigned short)(u >> 16);
}

__device__ __forceinline__ unsigned pack_bf162(float a, float b) {
    return (unsigned)bf16_rne(a) | ((unsigned)bf16_rne(b) << 16);
}

__device__ __forceinline__ bf16x8_t pack8(f32x4_t lo, f32x4_t hi) {
    union { bf16x8_t v; unsigned u[4]; } r;
    r.u[0] = pack_bf162(lo[0], lo[1]);
    r.u[1] = pack_bf162(lo[2], lo[3]);
    r.u[2] = pack_bf162(hi[0], hi[1]);
    r.u[3] = pack_bf162(hi[2], hi[3]);
    return r.v;
}

// gelu(x) = x * sigmoid(1.5957691*(x + 0.044715 x^3))  (tanh-form, max |err| vs exact erf ~5e-4)
//         = x - x * rcp(exp2(z) + 1),  z = x*(2.3022077 + 0.1029432*x^2)
__device__ __forceinline__ float gelu_fast(float x) {
    float u = x * x;
    float z = x * __builtin_fmaf(0.1029432f, u, 2.3022077f);
    float e = __builtin_amdgcn_exp2f(z);
    float r = __builtin_amdgcn_rcpf(e + 1.0f);
    return __builtin_fmaf(-x, r, x);
}

__global__ __launch_bounds__(256, 3) void neuron_mlp(
    const float* __restrict__ x, const float* __restrict__ w1,
    const float* __restrict__ w2, float* __restrict__ out)
{
    __shared__ unsigned short lw1[MIDD * SW1];
    __shared__ float lw2[MIDD];

    const int n    = blockIdx.x;
    const int tid  = threadIdx.x;
    const int wave = tid >> 6;
    const int lane = tid & 63;
    const int col  = lane & 15;   // A-row m / C-col mid / B-col mid
    const int quad = lane >> 4;   // k-chunk selector; C-row group

    // ---- stage W1_n transposed to LDS as bf16 [mid][k], once per block ----
    const float* w1n = w1 + (size_t)n * (HISTD * MIDD);
#pragma unroll
    for (int i = 0; i < 32; ++i) {
        int idx = tid + i * 256;           // 0..8191, coalesced global read
        int k   = idx >> 7;                // 0..63
        int mid = idx & 127;               // 0..127
        lw1[mid * SW1 + k] = bf16_rne(w1n[idx]);
    }
    if (tid < MIDD) lw2[tid] = w2[(size_t)n * MIDD + tid];
    __syncthreads();

    // ---- preload all B fragments (8 ntiles x 2 ksteps) into registers ----
    // B[k][mid]: lane holds k = ks*32 + quad*8 + j, mid = t*16 + col
    bf16x8_t bfrag[8][2];
#pragma unroll
    for (int t = 0; t < 8; ++t) {
#pragma unroll
        for (int ks = 0; ks < 2; ++ks) {
            const unsigned short* p = &lw1[(t * 16 + col) * SW1 + ks * 32 + quad * 8];
            bf16x8_t v;
#pragma unroll
            for (int j = 0; j < 8; ++j) v[j] = (short)p[j];
            bfrag[t][ks] = v;
        }
    }
    float w2v[8];
#pragma unroll
    for (int t = 0; t < 8; ++t) w2v[t] = lw2[t * 16 + col];

    const size_t rstride = (size_t)NRN * HISTD;            // 262144 floats between batch rows
    const float* xb = x + (size_t)n * HISTD + quad * 8;    // + b*rstride gives this lane's k-chunk

    // prefetch iteration 0
    f32x4_t r0, r1, r2, r3;
    {
        const float* p = xb + (size_t)(wave * 16 + col) * rstride;
        r0 = *(const f32x4_t*)(p + 0);
        r1 = *(const f32x4_t*)(p + 4);
        r2 = *(const f32x4_t*)(p + 32);
        r3 = *(const f32x4_t*)(p + 36);
    }

    for (int it = 0; it < 16; ++it) {
        bf16x8_t a0 = pack8(r0, r1);   // k = quad*8 .. +7      (K-step 0)
        bf16x8_t a1 = pack8(r2, r3);   // k = 32 + quad*8 .. +7 (K-step 1)

        if (it + 1 < 16) {             // prefetch next tile's x rows
            const float* p = xb + (size_t)((it + 1) * 64 + wave * 16 + col) * rstride;
            r0 = *(const f32x4_t*)(p + 0);
            r1 = *(const f32x4_t*)(p + 4);
            r2 = *(const f32x4_t*)(p + 32);
            r3 = *(const f32x4_t*)(p + 36);
        }

        f32x4_t acc[8];
#pragma unroll
        for (int t = 0; t < 8; ++t) {
            f32x4_t z = {0.f, 0.f, 0.f, 0.f};
            z      = __builtin_amdgcn_mfma_f32_16x16x32_bf16(a0, bfrag[t][0], z, 0, 0, 0);
            acc[t] = __builtin_amdgcn_mfma_f32_16x16x32_bf16(a1, bfrag[t][1], z, 0, 0, 0);
        }

        // epilogue: gelu + layer2 dot. lane holds h[row=quad*4+r][mid=t*16+col]
        float o[4] = {0.f, 0.f, 0.f, 0.f};
#pragma unroll
        for (int t = 0; t < 8; ++t) {
#pragma unroll
            for (int r = 0; r < 4; ++r)
                o[r] = __builtin_fmaf(gelu_fast(acc[t][r]), w2v[t], o[r]);
        }
        // reduce over the 16 mid-lanes (bits 0..3 of lane)
#pragma unroll
        for (int m = 1; m <= 8; m <<= 1) {
#pragma unroll
            for (int r = 0; r < 4; ++r) o[r] += __shfl_xor(o[r], m, 64);
        }
        if (col == 0) {
            int b0 = it * 64 + wave * 16 + quad * 4;
#pragma unroll
            for (int r = 0; r < 4; ++r)
                out[(size_t)(b0 + r) * NRN + n] = o[r];
        }
    }
}

extern "C" void kernel_launch(void* const* d_in, const int* in_sizes, int n_in,
                              void* d_out, int out_size, void* d_ws, size_t ws_size,
                              hipStream_t stream) {
    const float* x  = (const float*)d_in[0];
    const float* w1 = (const float*)d_in[1];
    const float* w2 = (const float*)d_in[2];
    float* out = (float*)d_out;
    neuron_mlp<<<dim3(NRN), dim3(256), 0, stream>>>(x, w1, w2, out);
}